// Round 16
// baseline (825.135 us; speedup 1.0000x reference)
//
#include <hip/hip_runtime.h>
#include <math.h>

#define BB 128
#define SS 1024
#define MM 64
#define KDIM 128
#define VDIM 256
#define FDIM 128
#define QNUM 5000
#define QD 5001            // q ids 0..5000
#define RROWS (4 * QD)     // 20004 distinct (r,q) rows

#define NW 16              // waves per k_rec block
#define LCH 64             // 16 equal chunks of 64 steps
#define MA 40              // accum pass A covers m [0,40)
#define MB 24              // pass B covers m [40,64)

#define QB 16                        // q's per EA block
#define NEA ((QD + QB - 1) / QB)     // 313 EA blocks
#define NPRE (NEA + QD + 128)        // total k_pre blocks

typedef _Float16 half2_t __attribute__((ext_vector_type(2)));
typedef float f2 __attribute__((ext_vector_type(2)));
typedef _Float16 f16x8 __attribute__((ext_vector_type(8)));
typedef float f32x4 __attribute__((ext_vector_type(4)));
union U4 { uint4 u; half2_t h[4]; };

#if defined(__has_builtin)
#if __has_builtin(__builtin_elementwise_fma)
#define HAVE_EFMA 1
#endif
#endif

__device__ __forceinline__ f2 pkfma(f2 a, f2 b, f2 c) {
#ifdef HAVE_EFMA
  return __builtin_elementwise_fma(a, b, c);
#else
  f2 r; r.x = fmaf(a.x, b.x, c.x); r.y = fmaf(a.y, b.y, c.y); return r;
#endif
}

__device__ __forceinline__ float sigmoidf_(float x) { return 1.0f / (1.0f + expf(-x)); }
__device__ __forceinline__ float softplusf_(float x) { return (x > 20.0f) ? x : log1pf(expf(x)); }

// ---------------- K_PRE: fused EA(affine-in-r) + per-q tables + Wh transpose ----------------
__global__ __launch_bounds__(256) void k_pre(
    const float* __restrict__ Wv, const float* __restrict__ bv,
    const float* __restrict__ We, const float* __restrict__ be,
    const float* __restrict__ Wa, const float* __restrict__ ba,
    const float* __restrict__ q_embed, const float* __restrict__ key_mem,
    const float* __restrict__ W_summary, const float* __restrict__ b_summary,
    const float* __restrict__ W_disc,
    const float* __restrict__ W_beta, const float* __restrict__ b_beta,
    float2* __restrict__ EA, float* __restrict__ w_tab,
    float* __restrict__ Sq_tab, float* __restrict__ aq_tab,
    float* __restrict__ beta_tab, _Float16* __restrict__ Wh)
{
  const int tid = threadIdx.x;
  const int blk = blockIdx.x;
  __shared__ __align__(16) float smem[2 * QB * 256];           // 32 KB
  __shared__ float s_small[KDIM + MM + FDIM];                  // qe | slog | s_half

  if (blk < NEA) {
    float* su = smem;
    float* sd = smem + QB * 256;
    const int qbase = blk * QB;
#pragma unroll
    for (int j = 0; j < QB; ++j) {
      const int q = qbase + j;
      float u = bv[tid], d = 0.f;
      if (q >= 1 && q < QD) {
        u += Wv[(size_t)(q - 1) * VDIM + tid];
        d = Wv[(size_t)(QNUM + q - 1) * VDIM + tid] * (1.0f / 3.0f);
      }
      su[j * 256 + tid] = u;
      sd[j * 256 + tid] = d;
    }
    __syncthreads();
    f2 aB[QB], aD[QB];
#pragma unroll
    for (int j = 0; j < QB; ++j) { aB[j] = (f2){0.f, 0.f}; aD[j] = (f2){0.f, 0.f}; }
    for (int i = 0; i < 256; i += 4) {
      f2 w0, w1, w2, w3;
      w0.x = We[(i + 0) * VDIM + tid]; w0.y = Wa[(i + 0) * VDIM + tid];
      w1.x = We[(i + 1) * VDIM + tid]; w1.y = Wa[(i + 1) * VDIM + tid];
      w2.x = We[(i + 2) * VDIM + tid]; w2.y = Wa[(i + 2) * VDIM + tid];
      w3.x = We[(i + 3) * VDIM + tid]; w3.y = Wa[(i + 3) * VDIM + tid];
#pragma unroll
      for (int j = 0; j < QB; ++j) {
        const float4 uu = *(const float4*)&su[j * 256 + i];
        const float4 dd = *(const float4*)&sd[j * 256 + i];
        aB[j] = pkfma((f2){uu.x, uu.x}, w0, aB[j]);
        aD[j] = pkfma((f2){dd.x, dd.x}, w0, aD[j]);
        aB[j] = pkfma((f2){uu.y, uu.y}, w1, aB[j]);
        aD[j] = pkfma((f2){dd.y, dd.y}, w1, aD[j]);
        aB[j] = pkfma((f2){uu.z, uu.z}, w2, aB[j]);
        aD[j] = pkfma((f2){dd.z, dd.z}, w2, aD[j]);
        aB[j] = pkfma((f2){uu.w, uu.w}, w3, aB[j]);
        aD[j] = pkfma((f2){dd.w, dd.w}, w3, aD[j]);
      }
    }
    const float bev = be[tid], bav = ba[tid];
#pragma unroll
    for (int j = 0; j < QB; ++j) {
      const int q = qbase + j;
      if (q < QD) {
        const float pe0 = aB[j].x + bev, pa0 = aB[j].y + bav;
        const float de = aD[j].x, da = aD[j].y;
#pragma unroll
        for (int r = 0; r < 4; ++r) {
          float2 p;
          p.x = sigmoidf_(fmaf((float)r, de, pe0));
          p.y = tanhf(fmaf((float)r, da, pa0));
          EA[(size_t)(r * QD + q) * VDIM + tid] = p;
        }
      }
    }
  } else if (blk < NEA + QD) {
    const int q = blk - NEA;
    const int wave = tid >> 6, l = tid & 63;
    float* s_key  = smem;
    float* qe     = s_small;
    float* slog   = s_small + KDIM;
    float* s_half = s_small + KDIM + MM;
    for (int i = tid; i < MM * KDIM; i += 256) s_key[i] = key_mem[i];
    if (tid < KDIM) qe[tid] = q_embed[(size_t)q * KDIM + tid];
    __syncthreads();
    {
      const int m = tid >> 2, j = tid & 3;
      const float* krow = s_key + m * KDIM + j * 32;
      const float* qrow = qe + j * 32;
      float acc = 0.f;
#pragma unroll
      for (int k = 0; k < 32; ++k) {
        const int i = (k + tid) & 31;
        acc = fmaf(qrow[i], krow[i], acc);
      }
      acc += __shfl_xor(acc, 1);
      acc += __shfl_xor(acc, 2);
      if (j == 0) slog[m] = acc;
    }
    __syncthreads();
    if (wave == 0) {
      const float x = slog[l];
      float mx = x;
#pragma unroll
      for (int o = 32; o; o >>= 1) mx = fmaxf(mx, __shfl_xor(mx, o));
      const float e = expf(x - mx);
      float s = e;
#pragma unroll
      for (int o = 32; o; o >>= 1) s += __shfl_xor(s, o);
      w_tab[(size_t)q * MM + l] = e / s;
    } else if (wave == 1) {
      float p = qe[l] * W_disc[KDIM + l] + qe[64 + l] * W_disc[KDIM + 64 + l];
#pragma unroll
      for (int o = 32; o; o >>= 1) p += __shfl_xor(p, o);
      if (l == 0) aq_tab[q] = p;
    } else if (wave == 2) {
      float p0 = qe[l] * W_beta[l * 3 + 0] + qe[64 + l] * W_beta[(64 + l) * 3 + 0];
      float p1 = qe[l] * W_beta[l * 3 + 1] + qe[64 + l] * W_beta[(64 + l) * 3 + 1];
      float p2 = qe[l] * W_beta[l * 3 + 2] + qe[64 + l] * W_beta[(64 + l) * 3 + 2];
#pragma unroll
      for (int o = 32; o; o >>= 1) {
        p0 += __shfl_xor(p0, o); p1 += __shfl_xor(p1, o); p2 += __shfl_xor(p2, o);
      }
      if (l == 0) {
        beta_tab[(size_t)q * 3 + 0] = p0 + b_beta[0];
        beta_tab[(size_t)q * 3 + 1] = p1 + b_beta[1];
        beta_tab[(size_t)q * 3 + 2] = p2 + b_beta[2];
      }
    }
    {
      const int f = tid & 127, h = tid >> 7;
      float acc = 0.f;
#pragma unroll 8
      for (int k = 0; k < 64; ++k)
        acc = fmaf(qe[h * 64 + k], W_summary[(size_t)(VDIM + h * 64 + k) * FDIM + f], acc);
      if (h == 1) s_half[f] = acc;
      __syncthreads();
      if (h == 0) Sq_tab[(size_t)q * FDIM + f] = acc + s_half[f] + b_summary[f];
    }
  } else {
    const int e = (blk - NEA - QD) * 256 + tid;
    const int f = e >> 8, k = e & 255;
    Wh[(size_t)f * 256 + k] = (_Float16)W_summary[(size_t)k * FDIM + f];
  }
}

// ---------------- K3: 16-wave chunked scan (2x resident waves per CU) ----------------
__global__ __launch_bounds__(1024, 1) void k_rec11(
    const int* __restrict__ q_data, const int* __restrict__ r_data,
    const float* __restrict__ init_mv,
    const float2* __restrict__ EA, const float* __restrict__ w_tab,
    _Float16* __restrict__ Rd)
{
  const int tid = threadIdx.x;
  const int wave = tid >> 6, lane = tid & 63;
  const int b = blockIdx.x >> 2, vc = blockIdx.x & 3;
  const int v = vc * 64 + lane;

  __shared__ int s_q[SS];
  __shared__ int s_r[SS];
  __shared__ __align__(16) float s_w[NW][8][MM];   // 32 KB per-wave ring
  __shared__ float s_R[MM * 64];                   // boundary state [m][lane]

  for (int i = tid; i < SS; i += 1024) {
    s_q[i] = q_data[b * SS + i];
    s_r[i] = r_data[b * SS + i];
  }
  __syncthreads();

  const int tb = wave * LCH;

  f2 mv2[MM / 2];
  f2 D2[MA / 2], U2[MA / 2];

  auto replay = [&](int base) {
    float eD[4], aD[4], wN[4];
#pragma unroll
    for (int j = 0; j < 4; ++j) {
      const int t = base + j;
      const float2 ea = EA[((size_t)(s_r[t] * QD + s_q[t])) * VDIM + v];
      eD[j] = ea.x; aD[j] = ea.y;
      s_w[wave][j][lane] = w_tab[(size_t)s_q[t] * MM + lane];
    }
    for (int g = 0; g < LCH / 4; ++g) {
      const int cb = (g & 1) << 2, nb = ((g + 1) & 1) << 2;
      float eN[4], aN[4];
#pragma unroll
      for (int j = 0; j < 4; ++j) {
        int tp = base + g * 4 + 4 + j; if (tp >= base + LCH) tp = base + g * 4 + j;
        const int q = s_q[tp];
        const float2 ea = EA[((size_t)(s_r[tp] * QD + q)) * VDIM + v];
        eN[j] = ea.x; aN[j] = ea.y;
        wN[j] = w_tab[(size_t)q * MM + lane];
      }
#pragma unroll
      for (int j = 0; j < 4; ++j) {
        const float4* w4 = (const float4*)s_w[wave][cb + j];
        const f2 e2 = {eD[j], eD[j]}, a2 = {aD[j], aD[j]};
        f2 rdA = {0.f, 0.f}, rdB = {0.f, 0.f};
#pragma unroll
        for (int k = 0; k < 16; ++k) {
          const float4 ww = w4[k];
          const f2 w0 = {ww.x, ww.y}, w1 = {ww.z, ww.w};
          rdA = pkfma(w0, mv2[2 * k], rdA);
          f2 t0 = pkfma(-e2, mv2[2 * k], a2);
          mv2[2 * k] = pkfma(w0, t0, mv2[2 * k]);
          rdB = pkfma(w1, mv2[2 * k + 1], rdB);
          f2 t1 = pkfma(-e2, mv2[2 * k + 1], a2);
          mv2[2 * k + 1] = pkfma(w1, t1, mv2[2 * k + 1]);
        }
        const f2 rs = rdA + rdB;
        Rd[((size_t)b * SS + base + g * 4 + j) * VDIM + v] = (_Float16)(rs.x + rs.y);
      }
#pragma unroll
      for (int j = 0; j < 4; ++j) s_w[wave][nb + j][lane] = wN[j];
#pragma unroll
      for (int j = 0; j < 4; ++j) { eD[j] = eN[j]; aD[j] = aN[j]; }
    }
  };

  auto accumA = [&](int base) {
#pragma unroll
    for (int k = 0; k < MA / 2; ++k) { D2[k] = (f2){1.f, 1.f}; U2[k] = (f2){0.f, 0.f}; }
    float eD[4], aD[4], wN[4];
#pragma unroll
    for (int j = 0; j < 4; ++j) {
      const int t = base + j;
      const float2 ea = EA[((size_t)(s_r[t] * QD + s_q[t])) * VDIM + v];
      eD[j] = ea.x; aD[j] = ea.y;
      s_w[wave][j][lane] = w_tab[(size_t)s_q[t] * MM + lane];
    }
    for (int g = 0; g < LCH / 4; ++g) {
      const int cb = (g & 1) << 2, nb = ((g + 1) & 1) << 2;
      float eN[4], aN[4];
#pragma unroll
      for (int j = 0; j < 4; ++j) {
        int tp = base + g * 4 + 4 + j; if (tp >= base + LCH) tp = base + g * 4 + j;
        const int q = s_q[tp];
        const float2 ea = EA[((size_t)(s_r[tp] * QD + q)) * VDIM + v];
        eN[j] = ea.x; aN[j] = ea.y;
        wN[j] = w_tab[(size_t)q * MM + lane];
      }
#pragma unroll
      for (int j = 0; j < 4; ++j) {
        const float4* w4 = (const float4*)s_w[wave][cb + j];
        const f2 e2 = {eD[j], eD[j]}, a2 = {aD[j], aD[j]};
#pragma unroll
        for (int k = 0; k < MA / 4; ++k) {
          const float4 ww = w4[k];
          const f2 w0 = {ww.x, ww.y}, w1 = {ww.z, ww.w};
          const f2 c0 = w0 * e2, c1 = w1 * e2;
          D2[2 * k]     = pkfma(-c0, D2[2 * k], D2[2 * k]);
          U2[2 * k]     = pkfma(-c0, U2[2 * k], U2[2 * k]);
          U2[2 * k]     = pkfma(w0, a2, U2[2 * k]);
          D2[2 * k + 1] = pkfma(-c1, D2[2 * k + 1], D2[2 * k + 1]);
          U2[2 * k + 1] = pkfma(-c1, U2[2 * k + 1], U2[2 * k + 1]);
          U2[2 * k + 1] = pkfma(w1, a2, U2[2 * k + 1]);
        }
      }
#pragma unroll
      for (int j = 0; j < 4; ++j) s_w[wave][nb + j][lane] = wN[j];
#pragma unroll
      for (int j = 0; j < 4; ++j) { eD[j] = eN[j]; aD[j] = aN[j]; }
    }
  };

  auto accumB = [&](int base) {
#pragma unroll
    for (int k = 0; k < MB / 2; ++k) { D2[k] = (f2){1.f, 1.f}; U2[k] = (f2){0.f, 0.f}; }
    float eD[4], aD[4], wN[4];
#pragma unroll
    for (int j = 0; j < 4; ++j) {
      const int t = base + j;
      const float2 ea = EA[((size_t)(s_r[t] * QD + s_q[t])) * VDIM + v];
      eD[j] = ea.x; aD[j] = ea.y;
      s_w[wave][j][lane] = w_tab[(size_t)s_q[t] * MM + lane];
    }
    for (int g = 0; g < LCH / 4; ++g) {
      const int cb = (g & 1) << 2, nb = ((g + 1) & 1) << 2;
      float eN[4], aN[4];
#pragma unroll
      for (int j = 0; j < 4; ++j) {
        int tp = base + g * 4 + 4 + j; if (tp >= base + LCH) tp = base + g * 4 + j;
        const int q = s_q[tp];
        const float2 ea = EA[((size_t)(s_r[tp] * QD + q)) * VDIM + v];
        eN[j] = ea.x; aN[j] = ea.y;
        wN[j] = w_tab[(size_t)q * MM + lane];
      }
#pragma unroll
      for (int j = 0; j < 4; ++j) {
        const float4* w4 = (const float4*)(s_w[wave][cb + j] + MA);
        const f2 e2 = {eD[j], eD[j]}, a2 = {aD[j], aD[j]};
#pragma unroll
        for (int k = 0; k < MB / 4; ++k) {
          const float4 ww = w4[k];
          const f2 w0 = {ww.x, ww.y}, w1 = {ww.z, ww.w};
          const f2 c0 = w0 * e2, c1 = w1 * e2;
          D2[2 * k]     = pkfma(-c0, D2[2 * k], D2[2 * k]);
          U2[2 * k]     = pkfma(-c0, U2[2 * k], U2[2 * k]);
          U2[2 * k]     = pkfma(w0, a2, U2[2 * k]);
          D2[2 * k + 1] = pkfma(-c1, D2[2 * k + 1], D2[2 * k + 1]);
          U2[2 * k + 1] = pkfma(-c1, U2[2 * k + 1], U2[2 * k + 1]);
          U2[2 * k + 1] = pkfma(w1, a2, U2[2 * k + 1]);
        }
      }
#pragma unroll
      for (int j = 0; j < 4; ++j) s_w[wave][nb + j][lane] = wN[j];
#pragma unroll
      for (int j = 0; j < 4; ++j) { eD[j] = eN[j]; aD[j] = aN[j]; }
    }
  };

  // ---- phase 1: wave0 replay chunk0 + publish; waves 1..15 accum pass A ----
  if (wave == 0) {
#pragma unroll
    for (int k = 0; k < MM / 2; ++k) {
      mv2[k].x = init_mv[(2 * k) * VDIM + v];
      mv2[k].y = init_mv[(2 * k + 1) * VDIM + v];
    }
    replay(0);
#pragma unroll
    for (int k = 0; k < MM / 2; ++k) {
      s_R[(2 * k) * 64 + lane] = mv2[k].x;
      s_R[(2 * k + 1) * 64 + lane] = mv2[k].y;
    }
  } else {
    accumA(tb);
  }
  __syncthreads();

  // ---- scan A ----
  for (int rr = 1; rr < NW; ++rr) {
    if (wave == rr) {
#pragma unroll
      for (int k = 0; k < MA / 2; ++k) {
        const float x0 = s_R[(2 * k) * 64 + lane];
        const float x1 = s_R[(2 * k + 1) * 64 + lane];
        s_R[(2 * k) * 64 + lane]     = fmaf(x0, D2[k].x, U2[k].x);
        s_R[(2 * k + 1) * 64 + lane] = fmaf(x1, D2[k].y, U2[k].y);
        mv2[k].x = x0; mv2[k].y = x1;
      }
    }
    __syncthreads();
  }

  // ---- phase 1B ----
  if (wave > 0) accumB(tb);
  __syncthreads();

  // ---- scan B ----
  for (int rr = 1; rr < NW; ++rr) {
    if (wave == rr) {
#pragma unroll
      for (int k = 0; k < MB / 2; ++k) {
        const float x0 = s_R[(MA + 2 * k) * 64 + lane];
        const float x1 = s_R[(MA + 2 * k + 1) * 64 + lane];
        s_R[(MA + 2 * k) * 64 + lane]     = fmaf(x0, D2[k].x, U2[k].x);
        s_R[(MA + 2 * k + 1) * 64 + lane] = fmaf(x1, D2[k].y, U2[k].y);
        mv2[MA / 2 + k].x = x0; mv2[MA / 2 + k].y = x1;
      }
    }
    __syncthreads();
  }

  // ---- phase 3: replay chunks 1..15 ----
  if (wave > 0) replay(tb);
}

// ---------------- K4: summary GEMM via MFMA + heads + CORAL ----------------
__global__ __launch_bounds__(256) void k_head(
    const int* __restrict__ q_data,
    const _Float16* __restrict__ Rd, const _Float16* __restrict__ Wh,
    const float* __restrict__ Sq_tab, const float* __restrict__ aq_tab,
    const float* __restrict__ beta_tab,
    const float* __restrict__ W_theta, const float* __restrict__ b_theta,
    const float* __restrict__ W_disc, const float* __restrict__ b_disc,
    const float* __restrict__ W_c1, const float* __restrict__ b_c1,
    const float* __restrict__ W_c2, const float* __restrict__ b_c2,
    const float* __restrict__ coral_w, const float* __restrict__ coral_b,
    float* __restrict__ out)
{
  const int tid = threadIdx.x;
  const int w = tid >> 6, l = tid & 63;
  const int rowbase = blockIdx.x * 64;
  const int b = rowbase >> 10;
  const int t0 = rowbase & (SS - 1);

  __shared__ __align__(16) _Float16 s_A[64 * 256];   // 32 KB
  __shared__ __align__(16) _Float16 s_sum[64 * 128]; // 16 KB
  __shared__ __align__(16) float s_h1[4][64];
  __shared__ int   s_q[64];
  __shared__ float s_aq[64];
  __shared__ float s_be[64][3];

  {
    const uint4* src = (const uint4*)(Rd + (size_t)rowbase * VDIM);
    uint4* dst = (uint4*)s_A;
    for (int i = tid; i < (64 * 256 * 2) / 16; i += 256) dst[i] = src[i];
  }
  if (tid < 64) {
    const int q = q_data[b * SS + t0 + tid];
    s_q[tid] = q;
    s_aq[tid] = aq_tab[q];
    s_be[tid][0] = beta_tab[(size_t)q * 3 + 0];
    s_be[tid][1] = beta_tab[(size_t)q * 3 + 1];
    s_be[tid][2] = beta_tab[(size_t)q * 3 + 2];
  }
  __syncthreads();

  {
    const int quad = l >> 4, r16 = l & 15;
    const int mrow = w * 16 + r16;
    f32x4 acc[8];
#pragma unroll
    for (int nt = 0; nt < 8; ++nt) acc[nt] = (f32x4){0.f, 0.f, 0.f, 0.f};
#pragma unroll
    for (int ks = 0; ks < 8; ++ks) {
      const f16x8 afrag = *(const f16x8*)(s_A + mrow * 256 + ks * 32 + quad * 8);
#pragma unroll
      for (int nt = 0; nt < 8; ++nt) {
        const int n = nt * 16 + r16;
        const f16x8 bfrag = *(const f16x8*)(Wh + (size_t)n * 256 + ks * 32 + quad * 8);
        acc[nt] = __builtin_amdgcn_mfma_f32_16x16x32_f16(afrag, bfrag, acc[nt], 0, 0, 0);
      }
    }
#pragma unroll
    for (int nt = 0; nt < 8; ++nt) {
#pragma unroll
      for (int reg = 0; reg < 4; ++reg) {
        const int row = w * 16 + quad * 4 + reg;
        const int col = nt * 16 + r16;
        const float val = acc[nt][reg] + Sq_tab[(size_t)s_q[row] * FDIM + col];
        s_sum[row * 128 + col] = (_Float16)tanhf(val);
      }
    }
  }
  __syncthreads();

  const float tw0 = W_theta[l], tw1 = W_theta[64 + l], tb = b_theta[0];
  const float dw0 = W_disc[l], dw1 = W_disc[64 + l], db = b_disc[0];
  float wc1reg[5];
#pragma unroll
  for (int i = 0; i < 5; ++i) wc1reg[i] = W_c1[i * 64 + l];
  const float bc1 = b_c1[l];
  const int jj = l >> 1, hh2 = l & 1;
  float wc2reg[32];
#pragma unroll
  for (int i = 0; i < 32; ++i) wc2reg[i] = W_c2[(hh2 * 32 + i) * 32 + jj];
  const float bc2 = b_c2[jj];
  const float cw = coral_w[jj];
  const float cb0 = coral_b[0], cb1 = coral_b[1], cb2 = coral_b[2];

  float* out_theta = out;
  float* out_beta  = out + (size_t)BB * SS;
  float* out_alpha = out + (size_t)BB * SS * 4;
  float* out_probs = out + (size_t)BB * SS * 5;
  float* out_logit = out + (size_t)BB * SS * 9;

  for (int rr = 0; rr < 16; ++rr) {
    const int r = w * 16 + rr;
    const float su0 = (float)s_sum[r * 128 + l];
    const float su1 = (float)s_sum[r * 128 + 64 + l];
    float at = su0 * tw0 + su1 * tw1;
    float ad = su0 * dw0 + su1 * dw1;
#pragma unroll
    for (int o = 32; o; o >>= 1) { at += __shfl_xor(at, o); ad += __shfl_xor(ad, o); }
    const float theta = (at + tb) * 3.0f;
    const float alpha = softplusf_(ad + s_aq[r] + db);
    const float be0 = s_be[r][0], be1 = s_be[r][1], be2 = s_be[r][2];
    float h1 = bc1;
    h1 = fmaf(theta, wc1reg[0], h1);
    h1 = fmaf(alpha, wc1reg[1], h1);
    h1 = fmaf(be0, wc1reg[2], h1);
    h1 = fmaf(be1, wc1reg[3], h1);
    h1 = fmaf(be2, wc1reg[4], h1);
    h1 = fmaxf(h1, 0.f);
    s_h1[w][l] = h1;
    float hacc = hh2 ? 0.f : bc2;
    const float4* h4 = (const float4*)s_h1[w];
#pragma unroll
    for (int k = 0; k < 8; ++k) {
      const float4 hv = h4[(hh2 << 3) + k];
      hacc = fmaf(hv.x, wc2reg[4 * k + 0], hacc);
      hacc = fmaf(hv.y, wc2reg[4 * k + 1], hacc);
      hacc = fmaf(hv.z, wc2reg[4 * k + 2], hacc);
      hacc = fmaf(hv.w, wc2reg[4 * k + 3], hacc);
    }
    hacc += __shfl_xor(hacc, 1);
    const float h2 = fmaxf(hacc, 0.f);
    float p = h2 * cw * 0.5f;
#pragma unroll
    for (int o = 32; o; o >>= 1) p += __shfl_xor(p, o);
    if (l == 0) {
      const float z = p;
      const float l0 = z + cb0, l1 = z + cb1, l2 = z + cb2;
      const float s0 = sigmoidf_(l0), s1 = sigmoidf_(l1), s2 = sigmoidf_(l2);
      const float q0 = s0, q1 = s0 * s1, q2 = s0 * s1 * s2;
      const size_t bt = (size_t)rowbase + r;
      out_theta[bt] = theta;
      out_alpha[bt] = alpha;
      out_beta[bt * 3 + 0] = be0;
      out_beta[bt * 3 + 1] = be1;
      out_beta[bt * 3 + 2] = be2;
      out_logit[bt * 3 + 0] = l0;
      out_logit[bt * 3 + 1] = l1;
      out_logit[bt * 3 + 2] = l2;
      out_probs[bt * 4 + 0] = 1.f - q0;
      out_probs[bt * 4 + 1] = q0 - q1;
      out_probs[bt * 4 + 2] = q1 - q2;
      out_probs[bt * 4 + 3] = q2;
    }
  }
}

extern "C" void kernel_launch(void* const* d_in, const int* in_sizes, int n_in,
                              void* d_out, int out_size, void* d_ws, size_t ws_size,
                              hipStream_t stream) {
  const int*   q_data    = (const int*)d_in[0];
  const int*   r_data    = (const int*)d_in[1];
  const float* q_embed   = (const float*)d_in[2];
  const float* key_mem   = (const float*)d_in[3];
  const float* init_mv   = (const float*)d_in[4];
  const float* W_value   = (const float*)d_in[5];
  const float* b_value   = (const float*)d_in[6];
  const float* W_erase   = (const float*)d_in[7];
  const float* b_erase   = (const float*)d_in[8];
  const float* W_add     = (const float*)d_in[9];
  const float* b_add     = (const float*)d_in[10];
  const float* W_summary = (const float*)d_in[11];
  const float* b_summary = (const float*)d_in[12];
  const float* W_theta   = (const float*)d_in[13];
  const float* b_theta   = (const float*)d_in[14];
  const float* W_beta    = (const float*)d_in[15];
  const float* b_beta    = (const float*)d_in[16];
  const float* W_disc    = (const float*)d_in[17];
  const float* b_disc    = (const float*)d_in[18];
  const float* W_c1      = (const float*)d_in[19];
  const float* b_c1      = (const float*)d_in[20];
  const float* W_c2      = (const float*)d_in[21];
  const float* b_c2      = (const float*)d_in[22];
  const float* coral_w   = (const float*)d_in[23];
  const float* coral_b   = (const float*)d_in[24];

  float* ws = (float*)d_ws;
  size_t off = 0;
  float2* EA      = (float2*)(ws + off); off += (size_t)RROWS * VDIM * 2;
  float* w_tab    = ws + off; off += (size_t)QD * MM;
  float* Sq_tab   = ws + off; off += (size_t)QD * FDIM;
  float* aq_tab   = ws + off; off += 5120;
  float* beta_tab = ws + off; off += 15104;
  _Float16* Wh = (_Float16*)(ws + off); off += (VDIM * FDIM) / 2;
  _Float16* Rd = (_Float16*)(ws + off);

  k_pre<<<dim3(NPRE), dim3(256), 0, stream>>>(
      W_value, b_value, W_erase, b_erase, W_add, b_add,
      q_embed, key_mem, W_summary, b_summary, W_disc, W_beta, b_beta,
      EA, w_tab, Sq_tab, aq_tab, beta_tab, Wh);

  k_rec11<<<dim3(BB * 4), dim3(1024), 0, stream>>>(
      q_data, r_data, init_mv, EA, w_tab, Rd);

  k_head<<<dim3((BB * SS) / 64), dim3(256), 0, stream>>>(
      q_data, Rd, Wh, Sq_tab, aq_tab, beta_tab,
      W_theta, b_theta, W_disc, b_disc,
      W_c1, b_c1, W_c2, b_c2, coral_w, coral_b, (float*)d_out);
}

// Round 17
// 815.175 us; speedup vs baseline: 1.0122x; 1.0122x over previous
//
#include <hip/hip_runtime.h>
#include <math.h>

#define BB 128
#define SS 1024
#define MM 64
#define KDIM 128
#define VDIM 256
#define FDIM 128
#define QNUM 5000
#define QD 5001            // q ids 0..5000
#define RROWS (4 * QD)     // 20004 distinct (r,q) rows

#define NW 16              // waves per k_rec block
#define LCH 64             // 16 equal chunks of 64 steps
#define MA 40              // accum pass A covers m [0,40)
#define MB 24              // pass B covers m [40,64)

#define QB 16                        // q's per EA block
#define NEA ((QD + QB - 1) / QB)     // 313 EA blocks
#define NPRE (NEA + QD + 128)        // total k_pre blocks

typedef _Float16 half2_t __attribute__((ext_vector_type(2)));
typedef float f2 __attribute__((ext_vector_type(2)));
typedef _Float16 f16x8 __attribute__((ext_vector_type(8)));
typedef float f32x4 __attribute__((ext_vector_type(4)));
union U4 { uint4 u; half2_t h[4]; };

#if defined(__has_builtin)
#if __has_builtin(__builtin_elementwise_fma)
#define HAVE_EFMA 1
#endif
#endif

__device__ __forceinline__ f2 pkfma(f2 a, f2 b, f2 c) {
#ifdef HAVE_EFMA
  return __builtin_elementwise_fma(a, b, c);
#else
  f2 r; r.x = fmaf(a.x, b.x, c.x); r.y = fmaf(a.y, b.y, c.y); return r;
#endif
}

__device__ __forceinline__ float sigmoidf_(float x) { return 1.0f / (1.0f + expf(-x)); }
__device__ __forceinline__ float softplusf_(float x) { return (x > 20.0f) ? x : log1pf(expf(x)); }

// ---------------- K_PRE: fused EA(affine-in-r) + per-q tables + Wh transpose ----------------
__global__ __launch_bounds__(256) void k_pre(
    const float* __restrict__ Wv, const float* __restrict__ bv,
    const float* __restrict__ We, const float* __restrict__ be,
    const float* __restrict__ Wa, const float* __restrict__ ba,
    const float* __restrict__ q_embed, const float* __restrict__ key_mem,
    const float* __restrict__ W_summary, const float* __restrict__ b_summary,
    const float* __restrict__ W_disc,
    const float* __restrict__ W_beta, const float* __restrict__ b_beta,
    float2* __restrict__ EA, float* __restrict__ w_tab,
    float* __restrict__ Sq_tab, float* __restrict__ aq_tab,
    float* __restrict__ beta_tab, _Float16* __restrict__ Wh)
{
  const int tid = threadIdx.x;
  const int blk = blockIdx.x;
  __shared__ __align__(16) float smem[2 * QB * 256];           // 32 KB
  __shared__ float s_small[KDIM + MM + FDIM];                  // qe | slog | s_half

  if (blk < NEA) {
    float* su = smem;
    float* sd = smem + QB * 256;
    const int qbase = blk * QB;
#pragma unroll
    for (int j = 0; j < QB; ++j) {
      const int q = qbase + j;
      float u = bv[tid], d = 0.f;
      if (q >= 1 && q < QD) {
        u += Wv[(size_t)(q - 1) * VDIM + tid];
        d = Wv[(size_t)(QNUM + q - 1) * VDIM + tid] * (1.0f / 3.0f);
      }
      su[j * 256 + tid] = u;
      sd[j * 256 + tid] = d;
    }
    __syncthreads();
    f2 aB[QB], aD[QB];
#pragma unroll
    for (int j = 0; j < QB; ++j) { aB[j] = (f2){0.f, 0.f}; aD[j] = (f2){0.f, 0.f}; }
    for (int i = 0; i < 256; i += 4) {
      f2 w0, w1, w2, w3;
      w0.x = We[(i + 0) * VDIM + tid]; w0.y = Wa[(i + 0) * VDIM + tid];
      w1.x = We[(i + 1) * VDIM + tid]; w1.y = Wa[(i + 1) * VDIM + tid];
      w2.x = We[(i + 2) * VDIM + tid]; w2.y = Wa[(i + 2) * VDIM + tid];
      w3.x = We[(i + 3) * VDIM + tid]; w3.y = Wa[(i + 3) * VDIM + tid];
#pragma unroll
      for (int j = 0; j < QB; ++j) {
        const float4 uu = *(const float4*)&su[j * 256 + i];
        const float4 dd = *(const float4*)&sd[j * 256 + i];
        aB[j] = pkfma((f2){uu.x, uu.x}, w0, aB[j]);
        aD[j] = pkfma((f2){dd.x, dd.x}, w0, aD[j]);
        aB[j] = pkfma((f2){uu.y, uu.y}, w1, aB[j]);
        aD[j] = pkfma((f2){dd.y, dd.y}, w1, aD[j]);
        aB[j] = pkfma((f2){uu.z, uu.z}, w2, aB[j]);
        aD[j] = pkfma((f2){dd.z, dd.z}, w2, aD[j]);
        aB[j] = pkfma((f2){uu.w, uu.w}, w3, aB[j]);
        aD[j] = pkfma((f2){dd.w, dd.w}, w3, aD[j]);
      }
    }
    const float bev = be[tid], bav = ba[tid];
#pragma unroll
    for (int j = 0; j < QB; ++j) {
      const int q = qbase + j;
      if (q < QD) {
        const float pe0 = aB[j].x + bev, pa0 = aB[j].y + bav;
        const float de = aD[j].x, da = aD[j].y;
#pragma unroll
        for (int r = 0; r < 4; ++r) {
          float2 p;
          p.x = sigmoidf_(fmaf((float)r, de, pe0));
          p.y = tanhf(fmaf((float)r, da, pa0));
          EA[(size_t)(r * QD + q) * VDIM + tid] = p;
        }
      }
    }
  } else if (blk < NEA + QD) {
    const int q = blk - NEA;
    const int wave = tid >> 6, l = tid & 63;
    float* s_key  = smem;
    float* qe     = s_small;
    float* slog   = s_small + KDIM;
    float* s_half = s_small + KDIM + MM;
    for (int i = tid; i < MM * KDIM; i += 256) s_key[i] = key_mem[i];
    if (tid < KDIM) qe[tid] = q_embed[(size_t)q * KDIM + tid];
    __syncthreads();
    {
      const int m = tid >> 2, j = tid & 3;
      const float* krow = s_key + m * KDIM + j * 32;
      const float* qrow = qe + j * 32;
      float acc = 0.f;
#pragma unroll
      for (int k = 0; k < 32; ++k) {
        const int i = (k + tid) & 31;
        acc = fmaf(qrow[i], krow[i], acc);
      }
      acc += __shfl_xor(acc, 1);
      acc += __shfl_xor(acc, 2);
      if (j == 0) slog[m] = acc;
    }
    __syncthreads();
    if (wave == 0) {
      const float x = slog[l];
      float mx = x;
#pragma unroll
      for (int o = 32; o; o >>= 1) mx = fmaxf(mx, __shfl_xor(mx, o));
      const float e = expf(x - mx);
      float s = e;
#pragma unroll
      for (int o = 32; o; o >>= 1) s += __shfl_xor(s, o);
      w_tab[(size_t)q * MM + l] = e / s;
    } else if (wave == 1) {
      float p = qe[l] * W_disc[KDIM + l] + qe[64 + l] * W_disc[KDIM + 64 + l];
#pragma unroll
      for (int o = 32; o; o >>= 1) p += __shfl_xor(p, o);
      if (l == 0) aq_tab[q] = p;
    } else if (wave == 2) {
      float p0 = qe[l] * W_beta[l * 3 + 0] + qe[64 + l] * W_beta[(64 + l) * 3 + 0];
      float p1 = qe[l] * W_beta[l * 3 + 1] + qe[64 + l] * W_beta[(64 + l) * 3 + 1];
      float p2 = qe[l] * W_beta[l * 3 + 2] + qe[64 + l] * W_beta[(64 + l) * 3 + 2];
#pragma unroll
      for (int o = 32; o; o >>= 1) {
        p0 += __shfl_xor(p0, o); p1 += __shfl_xor(p1, o); p2 += __shfl_xor(p2, o);
      }
      if (l == 0) {
        beta_tab[(size_t)q * 3 + 0] = p0 + b_beta[0];
        beta_tab[(size_t)q * 3 + 1] = p1 + b_beta[1];
        beta_tab[(size_t)q * 3 + 2] = p2 + b_beta[2];
      }
    }
    {
      const int f = tid & 127, h = tid >> 7;
      float acc = 0.f;
#pragma unroll 8
      for (int k = 0; k < 64; ++k)
        acc = fmaf(qe[h * 64 + k], W_summary[(size_t)(VDIM + h * 64 + k) * FDIM + f], acc);
      if (h == 1) s_half[f] = acc;
      __syncthreads();
      if (h == 0) Sq_tab[(size_t)q * FDIM + f] = acc + s_half[f] + b_summary[f];
    }
  } else {
    const int e = (blk - NEA - QD) * 256 + tid;
    const int f = e >> 8, k = e & 255;
    Wh[(size_t)f * 256 + k] = (_Float16)W_summary[(size_t)k * FDIM + f];
  }
}

// ---------------- K3: 16-wave chunked scan; launch_bounds(1024,4) pins 128-VGPR budget ----------------
__global__ __launch_bounds__(1024, 4) void k_rec12(
    const int* __restrict__ q_data, const int* __restrict__ r_data,
    const float* __restrict__ init_mv,
    const float2* __restrict__ EA, const float* __restrict__ w_tab,
    _Float16* __restrict__ Rd)
{
  const int tid = threadIdx.x;
  const int wave = tid >> 6, lane = tid & 63;
  const int b = blockIdx.x >> 2, vc = blockIdx.x & 3;
  const int v = vc * 64 + lane;

  __shared__ int s_q[SS];
  __shared__ int s_r[SS];
  __shared__ __align__(16) float s_w[NW][8][MM];   // 32 KB per-wave ring
  __shared__ float s_R[MM * 64];                   // boundary state [m][lane]

  for (int i = tid; i < SS; i += 1024) {
    s_q[i] = q_data[b * SS + i];
    s_r[i] = r_data[b * SS + i];
  }
  __syncthreads();

  const int tb = wave * LCH;

  f2 mv2[MM / 2];
  f2 D2[MA / 2], U2[MA / 2];

  auto replay = [&](int base) {
    float eD[4], aD[4], wN[4];
#pragma unroll
    for (int j = 0; j < 4; ++j) {
      const int t = base + j;
      const float2 ea = EA[((size_t)(s_r[t] * QD + s_q[t])) * VDIM + v];
      eD[j] = ea.x; aD[j] = ea.y;
      s_w[wave][j][lane] = w_tab[(size_t)s_q[t] * MM + lane];
    }
    for (int g = 0; g < LCH / 4; ++g) {
      const int cb = (g & 1) << 2, nb = ((g + 1) & 1) << 2;
      float eN[4], aN[4];
#pragma unroll
      for (int j = 0; j < 4; ++j) {
        int tp = base + g * 4 + 4 + j; if (tp >= base + LCH) tp = base + g * 4 + j;
        const int q = s_q[tp];
        const float2 ea = EA[((size_t)(s_r[tp] * QD + q)) * VDIM + v];
        eN[j] = ea.x; aN[j] = ea.y;
        wN[j] = w_tab[(size_t)q * MM + lane];
      }
#pragma unroll
      for (int j = 0; j < 4; ++j) {
        const float4* w4 = (const float4*)s_w[wave][cb + j];
        const f2 e2 = {eD[j], eD[j]}, a2 = {aD[j], aD[j]};
        f2 rdA = {0.f, 0.f}, rdB = {0.f, 0.f};
#pragma unroll
        for (int k = 0; k < 16; ++k) {
          const float4 ww = w4[k];
          const f2 w0 = {ww.x, ww.y}, w1 = {ww.z, ww.w};
          rdA = pkfma(w0, mv2[2 * k], rdA);
          f2 t0 = pkfma(-e2, mv2[2 * k], a2);
          mv2[2 * k] = pkfma(w0, t0, mv2[2 * k]);
          rdB = pkfma(w1, mv2[2 * k + 1], rdB);
          f2 t1 = pkfma(-e2, mv2[2 * k + 1], a2);
          mv2[2 * k + 1] = pkfma(w1, t1, mv2[2 * k + 1]);
        }
        const f2 rs = rdA + rdB;
        Rd[((size_t)b * SS + base + g * 4 + j) * VDIM + v] = (_Float16)(rs.x + rs.y);
      }
#pragma unroll
      for (int j = 0; j < 4; ++j) s_w[wave][nb + j][lane] = wN[j];
#pragma unroll
      for (int j = 0; j < 4; ++j) { eD[j] = eN[j]; aD[j] = aN[j]; }
    }
  };

  auto accumA = [&](int base) {
#pragma unroll
    for (int k = 0; k < MA / 2; ++k) { D2[k] = (f2){1.f, 1.f}; U2[k] = (f2){0.f, 0.f}; }
    float eD[4], aD[4], wN[4];
#pragma unroll
    for (int j = 0; j < 4; ++j) {
      const int t = base + j;
      const float2 ea = EA[((size_t)(s_r[t] * QD + s_q[t])) * VDIM + v];
      eD[j] = ea.x; aD[j] = ea.y;
      s_w[wave][j][lane] = w_tab[(size_t)s_q[t] * MM + lane];
    }
    for (int g = 0; g < LCH / 4; ++g) {
      const int cb = (g & 1) << 2, nb = ((g + 1) & 1) << 2;
      float eN[4], aN[4];
#pragma unroll
      for (int j = 0; j < 4; ++j) {
        int tp = base + g * 4 + 4 + j; if (tp >= base + LCH) tp = base + g * 4 + j;
        const int q = s_q[tp];
        const float2 ea = EA[((size_t)(s_r[tp] * QD + q)) * VDIM + v];
        eN[j] = ea.x; aN[j] = ea.y;
        wN[j] = w_tab[(size_t)q * MM + lane];
      }
#pragma unroll
      for (int j = 0; j < 4; ++j) {
        const float4* w4 = (const float4*)s_w[wave][cb + j];
        const f2 e2 = {eD[j], eD[j]}, a2 = {aD[j], aD[j]};
#pragma unroll
        for (int k = 0; k < MA / 4; ++k) {
          const float4 ww = w4[k];
          const f2 w0 = {ww.x, ww.y}, w1 = {ww.z, ww.w};
          const f2 c0 = w0 * e2, c1 = w1 * e2;
          D2[2 * k]     = pkfma(-c0, D2[2 * k], D2[2 * k]);
          U2[2 * k]     = pkfma(-c0, U2[2 * k], U2[2 * k]);
          U2[2 * k]     = pkfma(w0, a2, U2[2 * k]);
          D2[2 * k + 1] = pkfma(-c1, D2[2 * k + 1], D2[2 * k + 1]);
          U2[2 * k + 1] = pkfma(-c1, U2[2 * k + 1], U2[2 * k + 1]);
          U2[2 * k + 1] = pkfma(w1, a2, U2[2 * k + 1]);
        }
      }
#pragma unroll
      for (int j = 0; j < 4; ++j) s_w[wave][nb + j][lane] = wN[j];
#pragma unroll
      for (int j = 0; j < 4; ++j) { eD[j] = eN[j]; aD[j] = aN[j]; }
    }
  };

  auto accumB = [&](int base) {
#pragma unroll
    for (int k = 0; k < MB / 2; ++k) { D2[k] = (f2){1.f, 1.f}; U2[k] = (f2){0.f, 0.f}; }
    float eD[4], aD[4], wN[4];
#pragma unroll
    for (int j = 0; j < 4; ++j) {
      const int t = base + j;
      const float2 ea = EA[((size_t)(s_r[t] * QD + s_q[t])) * VDIM + v];
      eD[j] = ea.x; aD[j] = ea.y;
      s_w[wave][j][lane] = w_tab[(size_t)s_q[t] * MM + lane];
    }
    for (int g = 0; g < LCH / 4; ++g) {
      const int cb = (g & 1) << 2, nb = ((g + 1) & 1) << 2;
      float eN[4], aN[4];
#pragma unroll
      for (int j = 0; j < 4; ++j) {
        int tp = base + g * 4 + 4 + j; if (tp >= base + LCH) tp = base + g * 4 + j;
        const int q = s_q[tp];
        const float2 ea = EA[((size_t)(s_r[tp] * QD + q)) * VDIM + v];
        eN[j] = ea.x; aN[j] = ea.y;
        wN[j] = w_tab[(size_t)q * MM + lane];
      }
#pragma unroll
      for (int j = 0; j < 4; ++j) {
        const float4* w4 = (const float4*)(s_w[wave][cb + j] + MA);
        const f2 e2 = {eD[j], eD[j]}, a2 = {aD[j], aD[j]};
#pragma unroll
        for (int k = 0; k < MB / 4; ++k) {
          const float4 ww = w4[k];
          const f2 w0 = {ww.x, ww.y}, w1 = {ww.z, ww.w};
          const f2 c0 = w0 * e2, c1 = w1 * e2;
          D2[2 * k]     = pkfma(-c0, D2[2 * k], D2[2 * k]);
          U2[2 * k]     = pkfma(-c0, U2[2 * k], U2[2 * k]);
          U2[2 * k]     = pkfma(w0, a2, U2[2 * k]);
          D2[2 * k + 1] = pkfma(-c1, D2[2 * k + 1], D2[2 * k + 1]);
          U2[2 * k + 1] = pkfma(-c1, U2[2 * k + 1], U2[2 * k + 1]);
          U2[2 * k + 1] = pkfma(w1, a2, U2[2 * k + 1]);
        }
      }
#pragma unroll
      for (int j = 0; j < 4; ++j) s_w[wave][nb + j][lane] = wN[j];
#pragma unroll
      for (int j = 0; j < 4; ++j) { eD[j] = eN[j]; aD[j] = aN[j]; }
    }
  };

  // ---- phase 1: wave0 replay chunk0 + publish; waves 1..15 accum pass A ----
  if (wave == 0) {
#pragma unroll
    for (int k = 0; k < MM / 2; ++k) {
      mv2[k].x = init_mv[(2 * k) * VDIM + v];
      mv2[k].y = init_mv[(2 * k + 1) * VDIM + v];
    }
    replay(0);
#pragma unroll
    for (int k = 0; k < MM / 2; ++k) {
      s_R[(2 * k) * 64 + lane] = mv2[k].x;
      s_R[(2 * k + 1) * 64 + lane] = mv2[k].y;
    }
  } else {
    accumA(tb);
  }
  __syncthreads();

  // ---- scan A ----
  for (int rr = 1; rr < NW; ++rr) {
    if (wave == rr) {
#pragma unroll
      for (int k = 0; k < MA / 2; ++k) {
        const float x0 = s_R[(2 * k) * 64 + lane];
        const float x1 = s_R[(2 * k + 1) * 64 + lane];
        s_R[(2 * k) * 64 + lane]     = fmaf(x0, D2[k].x, U2[k].x);
        s_R[(2 * k + 1) * 64 + lane] = fmaf(x1, D2[k].y, U2[k].y);
        mv2[k].x = x0; mv2[k].y = x1;
      }
    }
    __syncthreads();
  }

  // ---- phase 1B ----
  if (wave > 0) accumB(tb);
  __syncthreads();

  // ---- scan B ----
  for (int rr = 1; rr < NW; ++rr) {
    if (wave == rr) {
#pragma unroll
      for (int k = 0; k < MB / 2; ++k) {
        const float x0 = s_R[(MA + 2 * k) * 64 + lane];
        const float x1 = s_R[(MA + 2 * k + 1) * 64 + lane];
        s_R[(MA + 2 * k) * 64 + lane]     = fmaf(x0, D2[k].x, U2[k].x);
        s_R[(MA + 2 * k + 1) * 64 + lane] = fmaf(x1, D2[k].y, U2[k].y);
        mv2[MA / 2 + k].x = x0; mv2[MA / 2 + k].y = x1;
      }
    }
    __syncthreads();
  }

  // ---- phase 3: replay chunks 1..15 ----
  if (wave > 0) replay(tb);
}

// ---------------- K4: summary GEMM via MFMA + heads + CORAL ----------------
__global__ __launch_bounds__(256) void k_head(
    const int* __restrict__ q_data,
    const _Float16* __restrict__ Rd, const _Float16* __restrict__ Wh,
    const float* __restrict__ Sq_tab, const float* __restrict__ aq_tab,
    const float* __restrict__ beta_tab,
    const float* __restrict__ W_theta, const float* __restrict__ b_theta,
    const float* __restrict__ W_disc, const float* __restrict__ b_disc,
    const float* __restrict__ W_c1, const float* __restrict__ b_c1,
    const float* __restrict__ W_c2, const float* __restrict__ b_c2,
    const float* __restrict__ coral_w, const float* __restrict__ coral_b,
    float* __restrict__ out)
{
  const int tid = threadIdx.x;
  const int w = tid >> 6, l = tid & 63;
  const int rowbase = blockIdx.x * 64;
  const int b = rowbase >> 10;
  const int t0 = rowbase & (SS - 1);

  __shared__ __align__(16) _Float16 s_A[64 * 256];   // 32 KB
  __shared__ __align__(16) _Float16 s_sum[64 * 128]; // 16 KB
  __shared__ __align__(16) float s_h1[4][64];
  __shared__ int   s_q[64];
  __shared__ float s_aq[64];
  __shared__ float s_be[64][3];

  {
    const uint4* src = (const uint4*)(Rd + (size_t)rowbase * VDIM);
    uint4* dst = (uint4*)s_A;
    for (int i = tid; i < (64 * 256 * 2) / 16; i += 256) dst[i] = src[i];
  }
  if (tid < 64) {
    const int q = q_data[b * SS + t0 + tid];
    s_q[tid] = q;
    s_aq[tid] = aq_tab[q];
    s_be[tid][0] = beta_tab[(size_t)q * 3 + 0];
    s_be[tid][1] = beta_tab[(size_t)q * 3 + 1];
    s_be[tid][2] = beta_tab[(size_t)q * 3 + 2];
  }
  __syncthreads();

  {
    const int quad = l >> 4, r16 = l & 15;
    const int mrow = w * 16 + r16;
    f32x4 acc[8];
#pragma unroll
    for (int nt = 0; nt < 8; ++nt) acc[nt] = (f32x4){0.f, 0.f, 0.f, 0.f};
#pragma unroll
    for (int ks = 0; ks < 8; ++ks) {
      const f16x8 afrag = *(const f16x8*)(s_A + mrow * 256 + ks * 32 + quad * 8);
#pragma unroll
      for (int nt = 0; nt < 8; ++nt) {
        const int n = nt * 16 + r16;
        const f16x8 bfrag = *(const f16x8*)(Wh + (size_t)n * 256 + ks * 32 + quad * 8);
        acc[nt] = __builtin_amdgcn_mfma_f32_16x16x32_f16(afrag, bfrag, acc[nt], 0, 0, 0);
      }
    }
#pragma unroll
    for (int nt = 0; nt < 8; ++nt) {
#pragma unroll
      for (int reg = 0; reg < 4; ++reg) {
        const int row = w * 16 + quad * 4 + reg;
        const int col = nt * 16 + r16;
        const float val = acc[nt][reg] + Sq_tab[(size_t)s_q[row] * FDIM + col];
        s_sum[row * 128 + col] = (_Float16)tanhf(val);
      }
    }
  }
  __syncthreads();

  const float tw0 = W_theta[l], tw1 = W_theta[64 + l], tb = b_theta[0];
  const float dw0 = W_disc[l], dw1 = W_disc[64 + l], db = b_disc[0];
  float wc1reg[5];
#pragma unroll
  for (int i = 0; i < 5; ++i) wc1reg[i] = W_c1[i * 64 + l];
  const float bc1 = b_c1[l];
  const int jj = l >> 1, hh2 = l & 1;
  float wc2reg[32];
#pragma unroll
  for (int i = 0; i < 32; ++i) wc2reg[i] = W_c2[(hh2 * 32 + i) * 32 + jj];
  const float bc2 = b_c2[jj];
  const float cw = coral_w[jj];
  const float cb0 = coral_b[0], cb1 = coral_b[1], cb2 = coral_b[2];

  float* out_theta = out;
  float* out_beta  = out + (size_t)BB * SS;
  float* out_alpha = out + (size_t)BB * SS * 4;
  float* out_probs = out + (size_t)BB * SS * 5;
  float* out_logit = out + (size_t)BB * SS * 9;

  for (int rr = 0; rr < 16; ++rr) {
    const int r = w * 16 + rr;
    const float su0 = (float)s_sum[r * 128 + l];
    const float su1 = (float)s_sum[r * 128 + 64 + l];
    float at = su0 * tw0 + su1 * tw1;
    float ad = su0 * dw0 + su1 * dw1;
#pragma unroll
    for (int o = 32; o; o >>= 1) { at += __shfl_xor(at, o); ad += __shfl_xor(ad, o); }
    const float theta = (at + tb) * 3.0f;
    const float alpha = softplusf_(ad + s_aq[r] + db);
    const float be0 = s_be[r][0], be1 = s_be[r][1], be2 = s_be[r][2];
    float h1 = bc1;
    h1 = fmaf(theta, wc1reg[0], h1);
    h1 = fmaf(alpha, wc1reg[1], h1);
    h1 = fmaf(be0, wc1reg[2], h1);
    h1 = fmaf(be1, wc1reg[3], h1);
    h1 = fmaf(be2, wc1reg[4], h1);
    h1 = fmaxf(h1, 0.f);
    s_h1[w][l] = h1;
    float hacc = hh2 ? 0.f : bc2;
    const float4* h4 = (const float4*)s_h1[w];
#pragma unroll
    for (int k = 0; k < 8; ++k) {
      const float4 hv = h4[(hh2 << 3) + k];
      hacc = fmaf(hv.x, wc2reg[4 * k + 0], hacc);
      hacc = fmaf(hv.y, wc2reg[4 * k + 1], hacc);
      hacc = fmaf(hv.z, wc2reg[4 * k + 2], hacc);
      hacc = fmaf(hv.w, wc2reg[4 * k + 3], hacc);
    }
    hacc += __shfl_xor(hacc, 1);
    const float h2 = fmaxf(hacc, 0.f);
    float p = h2 * cw * 0.5f;
#pragma unroll
    for (int o = 32; o; o >>= 1) p += __shfl_xor(p, o);
    if (l == 0) {
      const float z = p;
      const float l0 = z + cb0, l1 = z + cb1, l2 = z + cb2;
      const float s0 = sigmoidf_(l0), s1 = sigmoidf_(l1), s2 = sigmoidf_(l2);
      const float q0 = s0, q1 = s0 * s1, q2 = s0 * s1 * s2;
      const size_t bt = (size_t)rowbase + r;
      out_theta[bt] = theta;
      out_alpha[bt] = alpha;
      out_beta[bt * 3 + 0] = be0;
      out_beta[bt * 3 + 1] = be1;
      out_beta[bt * 3 + 2] = be2;
      out_logit[bt * 3 + 0] = l0;
      out_logit[bt * 3 + 1] = l1;
      out_logit[bt * 3 + 2] = l2;
      out_probs[bt * 4 + 0] = 1.f - q0;
      out_probs[bt * 4 + 1] = q0 - q1;
      out_probs[bt * 4 + 2] = q1 - q2;
      out_probs[bt * 4 + 3] = q2;
    }
  }
}

extern "C" void kernel_launch(void* const* d_in, const int* in_sizes, int n_in,
                              void* d_out, int out_size, void* d_ws, size_t ws_size,
                              hipStream_t stream) {
  const int*   q_data    = (const int*)d_in[0];
  const int*   r_data    = (const int*)d_in[1];
  const float* q_embed   = (const float*)d_in[2];
  const float* key_mem   = (const float*)d_in[3];
  const float* init_mv   = (const float*)d_in[4];
  const float* W_value   = (const float*)d_in[5];
  const float* b_value   = (const float*)d_in[6];
  const float* W_erase   = (const float*)d_in[7];
  const float* b_erase   = (const float*)d_in[8];
  const float* W_add     = (const float*)d_in[9];
  const float* b_add     = (const float*)d_in[10];
  const float* W_summary = (const float*)d_in[11];
  const float* b_summary = (const float*)d_in[12];
  const float* W_theta   = (const float*)d_in[13];
  const float* b_theta   = (const float*)d_in[14];
  const float* W_beta    = (const float*)d_in[15];
  const float* b_beta    = (const float*)d_in[16];
  const float* W_disc    = (const float*)d_in[17];
  const float* b_disc    = (const float*)d_in[18];
  const float* W_c1      = (const float*)d_in[19];
  const float* b_c1      = (const float*)d_in[20];
  const float* W_c2      = (const float*)d_in[21];
  const float* b_c2      = (const float*)d_in[22];
  const float* coral_w   = (const float*)d_in[23];
  const float* coral_b   = (const float*)d_in[24];

  float* ws = (float*)d_ws;
  size_t off = 0;
  float2* EA      = (float2*)(ws + off); off += (size_t)RROWS * VDIM * 2;
  float* w_tab    = ws + off; off += (size_t)QD * MM;
  float* Sq_tab   = ws + off; off += (size_t)QD * FDIM;
  float* aq_tab   = ws + off; off += 5120;
  float* beta_tab = ws + off; off += 15104;
  _Float16* Wh = (_Float16*)(ws + off); off += (VDIM * FDIM) / 2;
  _Float16* Rd = (_Float16*)(ws + off);

  k_pre<<<dim3(NPRE), dim3(256), 0, stream>>>(
      W_value, b_value, W_erase, b_erase, W_add, b_add,
      q_embed, key_mem, W_summary, b_summary, W_disc, W_beta, b_beta,
      EA, w_tab, Sq_tab, aq_tab, beta_tab, Wh);

  k_rec12<<<dim3(BB * 4), dim3(1024), 0, stream>>>(
      q_data, r_data, init_mv, EA, w_tab, Rd);

  k_head<<<dim3((BB * SS) / 64), dim3(256), 0, stream>>>(
      q_data, Rd, Wh, Sq_tab, aq_tab, beta_tab,
      W_theta, b_theta, W_disc, b_disc,
      W_c1, b_c1, W_c2, b_c2, coral_w, coral_b, (float*)d_out);
}

// Round 18
// 711.627 us; speedup vs baseline: 1.1595x; 1.1455x over previous
//
#include <hip/hip_runtime.h>
#include <math.h>

#define BB 128
#define SS 1024
#define MM 64
#define KDIM 128
#define VDIM 256
#define FDIM 128
#define QNUM 5000
#define QD 5001            // q ids 0..5000
#define RROWS (4 * QD)     // 20004 distinct (r,q) rows

#define LCH 128            // 8 equal chunks
#define MA 40              // accum pass A covers m [0,40)
#define MB 24              // pass B covers m [40,64)

#define QB 16                        // q's per EA block
#define NEA ((QD + QB - 1) / QB)     // 313 EA blocks
#define NPRE (NEA + QD + 128)        // total k_pre blocks

typedef _Float16 half2_t __attribute__((ext_vector_type(2)));
typedef float f2 __attribute__((ext_vector_type(2)));
typedef _Float16 f16x8 __attribute__((ext_vector_type(8)));
typedef float f32x4 __attribute__((ext_vector_type(4)));
union U4 { uint4 u; half2_t h[4]; };

#if defined(__has_builtin)
#if __has_builtin(__builtin_elementwise_fma)
#define HAVE_EFMA 1
#endif
#endif

__device__ __forceinline__ f2 pkfma(f2 a, f2 b, f2 c) {
#ifdef HAVE_EFMA
  return __builtin_elementwise_fma(a, b, c);
#else
  f2 r; r.x = fmaf(a.x, b.x, c.x); r.y = fmaf(a.y, b.y, c.y); return r;
#endif
}

__device__ __forceinline__ float sigmoidf_(float x) { return 1.0f / (1.0f + expf(-x)); }
__device__ __forceinline__ float softplusf_(float x) { return (x > 20.0f) ? x : log1pf(expf(x)); }

// ---------------- K_PRE: fused EA(affine-in-r) + per-q tables + Wh transpose ----------------
__global__ __launch_bounds__(256) void k_pre(
    const float* __restrict__ Wv, const float* __restrict__ bv,
    const float* __restrict__ We, const float* __restrict__ be,
    const float* __restrict__ Wa, const float* __restrict__ ba,
    const float* __restrict__ q_embed, const float* __restrict__ key_mem,
    const float* __restrict__ W_summary, const float* __restrict__ b_summary,
    const float* __restrict__ W_disc,
    const float* __restrict__ W_beta, const float* __restrict__ b_beta,
    float2* __restrict__ EA, float* __restrict__ w_tab,
    float* __restrict__ Sq_tab, float* __restrict__ aq_tab,
    float* __restrict__ beta_tab, _Float16* __restrict__ Wh)
{
  const int tid = threadIdx.x;
  const int blk = blockIdx.x;
  __shared__ __align__(16) float smem[2 * QB * 256];           // 32 KB
  __shared__ float s_small[KDIM + MM + FDIM];                  // qe | slog | s_half

  if (blk < NEA) {
    float* su = smem;
    float* sd = smem + QB * 256;
    const int qbase = blk * QB;
#pragma unroll
    for (int j = 0; j < QB; ++j) {
      const int q = qbase + j;
      float u = bv[tid], d = 0.f;
      if (q >= 1 && q < QD) {
        u += Wv[(size_t)(q - 1) * VDIM + tid];
        d = Wv[(size_t)(QNUM + q - 1) * VDIM + tid] * (1.0f / 3.0f);
      }
      su[j * 256 + tid] = u;
      sd[j * 256 + tid] = d;
    }
    __syncthreads();
    f2 aB[QB], aD[QB];
#pragma unroll
    for (int j = 0; j < QB; ++j) { aB[j] = (f2){0.f, 0.f}; aD[j] = (f2){0.f, 0.f}; }
    for (int i = 0; i < 256; i += 4) {
      f2 w0, w1, w2, w3;
      w0.x = We[(i + 0) * VDIM + tid]; w0.y = Wa[(i + 0) * VDIM + tid];
      w1.x = We[(i + 1) * VDIM + tid]; w1.y = Wa[(i + 1) * VDIM + tid];
      w2.x = We[(i + 2) * VDIM + tid]; w2.y = Wa[(i + 2) * VDIM + tid];
      w3.x = We[(i + 3) * VDIM + tid]; w3.y = Wa[(i + 3) * VDIM + tid];
#pragma unroll
      for (int j = 0; j < QB; ++j) {
        const float4 uu = *(const float4*)&su[j * 256 + i];
        const float4 dd = *(const float4*)&sd[j * 256 + i];
        aB[j] = pkfma((f2){uu.x, uu.x}, w0, aB[j]);
        aD[j] = pkfma((f2){dd.x, dd.x}, w0, aD[j]);
        aB[j] = pkfma((f2){uu.y, uu.y}, w1, aB[j]);
        aD[j] = pkfma((f2){dd.y, dd.y}, w1, aD[j]);
        aB[j] = pkfma((f2){uu.z, uu.z}, w2, aB[j]);
        aD[j] = pkfma((f2){dd.z, dd.z}, w2, aD[j]);
        aB[j] = pkfma((f2){uu.w, uu.w}, w3, aB[j]);
        aD[j] = pkfma((f2){dd.w, dd.w}, w3, aD[j]);
      }
    }
    const float bev = be[tid], bav = ba[tid];
#pragma unroll
    for (int j = 0; j < QB; ++j) {
      const int q = qbase + j;
      if (q < QD) {
        const float pe0 = aB[j].x + bev, pa0 = aB[j].y + bav;
        const float de = aD[j].x, da = aD[j].y;
#pragma unroll
        for (int r = 0; r < 4; ++r) {
          float2 p;
          p.x = sigmoidf_(fmaf((float)r, de, pe0));
          p.y = tanhf(fmaf((float)r, da, pa0));
          EA[(size_t)(r * QD + q) * VDIM + tid] = p;
        }
      }
    }
  } else if (blk < NEA + QD) {
    const int q = blk - NEA;
    const int wave = tid >> 6, l = tid & 63;
    float* s_key  = smem;
    float* qe     = s_small;
    float* slog   = s_small + KDIM;
    float* s_half = s_small + KDIM + MM;
    for (int i = tid; i < MM * KDIM; i += 256) s_key[i] = key_mem[i];
    if (tid < KDIM) qe[tid] = q_embed[(size_t)q * KDIM + tid];
    __syncthreads();
    {
      const int m = tid >> 2, j = tid & 3;
      const float* krow = s_key + m * KDIM + j * 32;
      const float* qrow = qe + j * 32;
      float acc = 0.f;
#pragma unroll
      for (int k = 0; k < 32; ++k) {
        const int i = (k + tid) & 31;
        acc = fmaf(qrow[i], krow[i], acc);
      }
      acc += __shfl_xor(acc, 1);
      acc += __shfl_xor(acc, 2);
      if (j == 0) slog[m] = acc;
    }
    __syncthreads();
    if (wave == 0) {
      const float x = slog[l];
      float mx = x;
#pragma unroll
      for (int o = 32; o; o >>= 1) mx = fmaxf(mx, __shfl_xor(mx, o));
      const float e = expf(x - mx);
      float s = e;
#pragma unroll
      for (int o = 32; o; o >>= 1) s += __shfl_xor(s, o);
      w_tab[(size_t)q * MM + l] = e / s;
    } else if (wave == 1) {
      float p = qe[l] * W_disc[KDIM + l] + qe[64 + l] * W_disc[KDIM + 64 + l];
#pragma unroll
      for (int o = 32; o; o >>= 1) p += __shfl_xor(p, o);
      if (l == 0) aq_tab[q] = p;
    } else if (wave == 2) {
      float p0 = qe[l] * W_beta[l * 3 + 0] + qe[64 + l] * W_beta[(64 + l) * 3 + 0];
      float p1 = qe[l] * W_beta[l * 3 + 1] + qe[64 + l] * W_beta[(64 + l) * 3 + 1];
      float p2 = qe[l] * W_beta[l * 3 + 2] + qe[64 + l] * W_beta[(64 + l) * 3 + 2];
#pragma unroll
      for (int o = 32; o; o >>= 1) {
        p0 += __shfl_xor(p0, o); p1 += __shfl_xor(p1, o); p2 += __shfl_xor(p2, o);
      }
      if (l == 0) {
        beta_tab[(size_t)q * 3 + 0] = p0 + b_beta[0];
        beta_tab[(size_t)q * 3 + 1] = p1 + b_beta[1];
        beta_tab[(size_t)q * 3 + 2] = p2 + b_beta[2];
      }
    }
    {
      const int f = tid & 127, h = tid >> 7;
      float acc = 0.f;
#pragma unroll 8
      for (int k = 0; k < 64; ++k)
        acc = fmaf(qe[h * 64 + k], W_summary[(size_t)(VDIM + h * 64 + k) * FDIM + f], acc);
      if (h == 1) s_half[f] = acc;
      __syncthreads();
      if (h == 0) Sq_tab[(size_t)q * FDIM + f] = acc + s_half[f] + b_summary[f];
    }
  } else {
    const int e = (blk - NEA - QD) * 256 + tid;
    const int f = e >> 8, k = e & 255;
    Wh[(size_t)f * 256 + k] = (_Float16)W_summary[(size_t)k * FDIM + f];
  }
}

// ---------------- K3: R8/R15 k_rec6 — f32 LDS ring, load->compute->ds_write ----------------
__global__ __launch_bounds__(512, 2) void k_rec6(
    const int* __restrict__ q_data, const int* __restrict__ r_data,
    const float* __restrict__ init_mv,
    const float2* __restrict__ EA, const float* __restrict__ w_tab,
    _Float16* __restrict__ Rd)
{
  const int tid = threadIdx.x;
  const int wave = tid >> 6, lane = tid & 63;
  const int b = blockIdx.x >> 2, vc = blockIdx.x & 3;
  const int v = vc * 64 + lane;

  __shared__ int s_q[SS];
  __shared__ int s_r[SS];
  __shared__ __align__(16) float s_w[8][8][MM];
  __shared__ float s_R[MM * 64];

  for (int i = tid; i < SS; i += 512) {
    s_q[i] = q_data[b * SS + i];
    s_r[i] = r_data[b * SS + i];
  }
  __syncthreads();

  const int tb = wave * LCH;

  f2 mv2[MM / 2];
  f2 D2[MA / 2], U2[MA / 2];

  auto replay = [&](int base) {
    float eD[4], aD[4], wN[4];
#pragma unroll
    for (int j = 0; j < 4; ++j) {
      const int t = base + j;
      const float2 ea = EA[((size_t)(s_r[t] * QD + s_q[t])) * VDIM + v];
      eD[j] = ea.x; aD[j] = ea.y;
      s_w[wave][j][lane] = w_tab[(size_t)s_q[t] * MM + lane];
    }
    for (int g = 0; g < LCH / 4; ++g) {
      const int cb = (g & 1) << 2, nb = ((g + 1) & 1) << 2;
      float eN[4], aN[4];
#pragma unroll
      for (int j = 0; j < 4; ++j) {
        int tp = base + g * 4 + 4 + j; if (tp >= base + LCH) tp = base + g * 4 + j;
        const int q = s_q[tp];
        const float2 ea = EA[((size_t)(s_r[tp] * QD + q)) * VDIM + v];
        eN[j] = ea.x; aN[j] = ea.y;
        wN[j] = w_tab[(size_t)q * MM + lane];
      }
#pragma unroll
      for (int j = 0; j < 4; ++j) {
        const float4* w4 = (const float4*)s_w[wave][cb + j];
        const f2 e2 = {eD[j], eD[j]}, a2 = {aD[j], aD[j]};
        f2 rdA = {0.f, 0.f}, rdB = {0.f, 0.f};
#pragma unroll
        for (int k = 0; k < 16; ++k) {
          const float4 ww = w4[k];
          const f2 w0 = {ww.x, ww.y}, w1 = {ww.z, ww.w};
          rdA = pkfma(w0, mv2[2 * k], rdA);
          f2 t0 = pkfma(-e2, mv2[2 * k], a2);
          mv2[2 * k] = pkfma(w0, t0, mv2[2 * k]);
          rdB = pkfma(w1, mv2[2 * k + 1], rdB);
          f2 t1 = pkfma(-e2, mv2[2 * k + 1], a2);
          mv2[2 * k + 1] = pkfma(w1, t1, mv2[2 * k + 1]);
        }
        const f2 rs = rdA + rdB;
        Rd[((size_t)b * SS + base + g * 4 + j) * VDIM + v] = (_Float16)(rs.x + rs.y);
      }
#pragma unroll
      for (int j = 0; j < 4; ++j) s_w[wave][nb + j][lane] = wN[j];
#pragma unroll
      for (int j = 0; j < 4; ++j) { eD[j] = eN[j]; aD[j] = aN[j]; }
    }
  };

  auto accumA = [&](int base) {
#pragma unroll
    for (int k = 0; k < MA / 2; ++k) { D2[k] = (f2){1.f, 1.f}; U2[k] = (f2){0.f, 0.f}; }
    float eD[4], aD[4], wN[4];
#pragma unroll
    for (int j = 0; j < 4; ++j) {
      const int t = base + j;
      const float2 ea = EA[((size_t)(s_r[t] * QD + s_q[t])) * VDIM + v];
      eD[j] = ea.x; aD[j] = ea.y;
      s_w[wave][j][lane] = w_tab[(size_t)s_q[t] * MM + lane];
    }
    for (int g = 0; g < LCH / 4; ++g) {
      const int cb = (g & 1) << 2, nb = ((g + 1) & 1) << 2;
      float eN[4], aN[4];
#pragma unroll
      for (int j = 0; j < 4; ++j) {
        int tp = base + g * 4 + 4 + j; if (tp >= base + LCH) tp = base + g * 4 + j;
        const int q = s_q[tp];
        const float2 ea = EA[((size_t)(s_r[tp] * QD + q)) * VDIM + v];
        eN[j] = ea.x; aN[j] = ea.y;
        wN[j] = w_tab[(size_t)q * MM + lane];
      }
#pragma unroll
      for (int j = 0; j < 4; ++j) {
        const float4* w4 = (const float4*)s_w[wave][cb + j];
        const f2 e2 = {eD[j], eD[j]}, a2 = {aD[j], aD[j]};
#pragma unroll
        for (int k = 0; k < MA / 4; ++k) {
          const float4 ww = w4[k];
          const f2 w0 = {ww.x, ww.y}, w1 = {ww.z, ww.w};
          const f2 c0 = w0 * e2, c1 = w1 * e2;
          D2[2 * k]     = pkfma(-c0, D2[2 * k], D2[2 * k]);
          U2[2 * k]     = pkfma(-c0, U2[2 * k], U2[2 * k]);
          U2[2 * k]     = pkfma(w0, a2, U2[2 * k]);
          D2[2 * k + 1] = pkfma(-c1, D2[2 * k + 1], D2[2 * k + 1]);
          U2[2 * k + 1] = pkfma(-c1, U2[2 * k + 1], U2[2 * k + 1]);
          U2[2 * k + 1] = pkfma(w1, a2, U2[2 * k + 1]);
        }
      }
#pragma unroll
      for (int j = 0; j < 4; ++j) s_w[wave][nb + j][lane] = wN[j];
#pragma unroll
      for (int j = 0; j < 4; ++j) { eD[j] = eN[j]; aD[j] = aN[j]; }
    }
  };

  auto accumB = [&](int base) {
#pragma unroll
    for (int k = 0; k < MB / 2; ++k) { D2[k] = (f2){1.f, 1.f}; U2[k] = (f2){0.f, 0.f}; }
    float eD[4], aD[4], wN[4];
#pragma unroll
    for (int j = 0; j < 4; ++j) {
      const int t = base + j;
      const float2 ea = EA[((size_t)(s_r[t] * QD + s_q[t])) * VDIM + v];
      eD[j] = ea.x; aD[j] = ea.y;
      s_w[wave][j][lane] = w_tab[(size_t)s_q[t] * MM + lane];
    }
    for (int g = 0; g < LCH / 4; ++g) {
      const int cb = (g & 1) << 2, nb = ((g + 1) & 1) << 2;
      float eN[4], aN[4];
#pragma unroll
      for (int j = 0; j < 4; ++j) {
        int tp = base + g * 4 + 4 + j; if (tp >= base + LCH) tp = base + g * 4 + j;
        const int q = s_q[tp];
        const float2 ea = EA[((size_t)(s_r[tp] * QD + q)) * VDIM + v];
        eN[j] = ea.x; aN[j] = ea.y;
        wN[j] = w_tab[(size_t)q * MM + lane];
      }
#pragma unroll
      for (int j = 0; j < 4; ++j) {
        const float4* w4 = (const float4*)(s_w[wave][cb + j] + MA);
        const f2 e2 = {eD[j], eD[j]}, a2 = {aD[j], aD[j]};
#pragma unroll
        for (int k = 0; k < MB / 4; ++k) {
          const float4 ww = w4[k];
          const f2 w0 = {ww.x, ww.y}, w1 = {ww.z, ww.w};
          const f2 c0 = w0 * e2, c1 = w1 * e2;
          D2[2 * k]     = pkfma(-c0, D2[2 * k], D2[2 * k]);
          U2[2 * k]     = pkfma(-c0, U2[2 * k], U2[2 * k]);
          U2[2 * k]     = pkfma(w0, a2, U2[2 * k]);
          D2[2 * k + 1] = pkfma(-c1, D2[2 * k + 1], D2[2 * k + 1]);
          U2[2 * k + 1] = pkfma(-c1, U2[2 * k + 1], U2[2 * k + 1]);
          U2[2 * k + 1] = pkfma(w1, a2, U2[2 * k + 1]);
        }
      }
#pragma unroll
      for (int j = 0; j < 4; ++j) s_w[wave][nb + j][lane] = wN[j];
#pragma unroll
      for (int j = 0; j < 4; ++j) { eD[j] = eN[j]; aD[j] = aN[j]; }
    }
  };

  if (wave == 0) {
#pragma unroll
    for (int k = 0; k < MM / 2; ++k) {
      mv2[k].x = init_mv[(2 * k) * VDIM + v];
      mv2[k].y = init_mv[(2 * k + 1) * VDIM + v];
    }
    replay(0);
#pragma unroll
    for (int k = 0; k < MM / 2; ++k) {
      s_R[(2 * k) * 64 + lane] = mv2[k].x;
      s_R[(2 * k + 1) * 64 + lane] = mv2[k].y;
    }
  } else {
    accumA(tb);
  }
  __syncthreads();

  for (int rr = 1; rr < 8; ++rr) {
    if (wave == rr) {
#pragma unroll
      for (int k = 0; k < MA / 2; ++k) {
        const float x0 = s_R[(2 * k) * 64 + lane];
        const float x1 = s_R[(2 * k + 1) * 64 + lane];
        s_R[(2 * k) * 64 + lane]     = fmaf(x0, D2[k].x, U2[k].x);
        s_R[(2 * k + 1) * 64 + lane] = fmaf(x1, D2[k].y, U2[k].y);
        mv2[k].x = x0; mv2[k].y = x1;
      }
    }
    __syncthreads();
  }

  if (wave > 0) accumB(tb);
  __syncthreads();

  for (int rr = 1; rr < 8; ++rr) {
    if (wave == rr) {
#pragma unroll
      for (int k = 0; k < MB / 2; ++k) {
        const float x0 = s_R[(MA + 2 * k) * 64 + lane];
        const float x1 = s_R[(MA + 2 * k + 1) * 64 + lane];
        s_R[(MA + 2 * k) * 64 + lane]     = fmaf(x0, D2[k].x, U2[k].x);
        s_R[(MA + 2 * k + 1) * 64 + lane] = fmaf(x1, D2[k].y, U2[k].y);
        mv2[MA / 2 + k].x = x0; mv2[MA / 2 + k].y = x1;
      }
    }
    __syncthreads();
  }

  if (wave > 0) replay(tb);
}

// ---------------- K4: summary GEMM via MFMA + heads + CORAL ----------------
__global__ __launch_bounds__(256) void k_head(
    const int* __restrict__ q_data,
    const _Float16* __restrict__ Rd, const _Float16* __restrict__ Wh,
    const float* __restrict__ Sq_tab, const float* __restrict__ aq_tab,
    const float* __restrict__ beta_tab,
    const float* __restrict__ W_theta, const float* __restrict__ b_theta,
    const float* __restrict__ W_disc, const float* __restrict__ b_disc,
    const float* __restrict__ W_c1, const float* __restrict__ b_c1,
    const float* __restrict__ W_c2, const float* __restrict__ b_c2,
    const float* __restrict__ coral_w, const float* __restrict__ coral_b,
    float* __restrict__ out)
{
  const int tid = threadIdx.x;
  const int w = tid >> 6, l = tid & 63;
  const int rowbase = blockIdx.x * 64;
  const int b = rowbase >> 10;
  const int t0 = rowbase & (SS - 1);

  __shared__ __align__(16) _Float16 s_A[64 * 256];   // 32 KB
  __shared__ __align__(16) _Float16 s_sum[64 * 128]; // 16 KB
  __shared__ __align__(16) float s_h1[4][64];
  __shared__ int   s_q[64];
  __shared__ float s_aq[64];
  __shared__ float s_be[64][3];

  {
    const uint4* src = (const uint4*)(Rd + (size_t)rowbase * VDIM);
    uint4* dst = (uint4*)s_A;
    for (int i = tid; i < (64 * 256 * 2) / 16; i += 256) dst[i] = src[i];
  }
  if (tid < 64) {
    const int q = q_data[b * SS + t0 + tid];
    s_q[tid] = q;
    s_aq[tid] = aq_tab[q];
    s_be[tid][0] = beta_tab[(size_t)q * 3 + 0];
    s_be[tid][1] = beta_tab[(size_t)q * 3 + 1];
    s_be[tid][2] = beta_tab[(size_t)q * 3 + 2];
  }
  __syncthreads();

  {
    const int quad = l >> 4, r16 = l & 15;
    const int mrow = w * 16 + r16;
    f32x4 acc[8];
#pragma unroll
    for (int nt = 0; nt < 8; ++nt) acc[nt] = (f32x4){0.f, 0.f, 0.f, 0.f};
#pragma unroll
    for (int ks = 0; ks < 8; ++ks) {
      const f16x8 afrag = *(const f16x8*)(s_A + mrow * 256 + ks * 32 + quad * 8);
#pragma unroll
      for (int nt = 0; nt < 8; ++nt) {
        const int n = nt * 16 + r16;
        const f16x8 bfrag = *(const f16x8*)(Wh + (size_t)n * 256 + ks * 32 + quad * 8);
        acc[nt] = __builtin_amdgcn_mfma_f32_16x16x32_f16(afrag, bfrag, acc[nt], 0, 0, 0);
      }
    }
#pragma unroll
    for (int nt = 0; nt < 8; ++nt) {
#pragma unroll
      for (int reg = 0; reg < 4; ++reg) {
        const int row = w * 16 + quad * 4 + reg;
        const int col = nt * 16 + r16;
        const float val = acc[nt][reg] + Sq_tab[(size_t)s_q[row] * FDIM + col];
        s_sum[row * 128 + col] = (_Float16)tanhf(val);
      }
    }
  }
  __syncthreads();

  const float tw0 = W_theta[l], tw1 = W_theta[64 + l], tb = b_theta[0];
  const float dw0 = W_disc[l], dw1 = W_disc[64 + l], db = b_disc[0];
  float wc1reg[5];
#pragma unroll
  for (int i = 0; i < 5; ++i) wc1reg[i] = W_c1[i * 64 + l];
  const float bc1 = b_c1[l];
  const int jj = l >> 1, hh2 = l & 1;
  float wc2reg[32];
#pragma unroll
  for (int i = 0; i < 32; ++i) wc2reg[i] = W_c2[(hh2 * 32 + i) * 32 + jj];
  const float bc2 = b_c2[jj];
  const float cw = coral_w[jj];
  const float cb0 = coral_b[0], cb1 = coral_b[1], cb2 = coral_b[2];

  float* out_theta = out;
  float* out_beta  = out + (size_t)BB * SS;
  float* out_alpha = out + (size_t)BB * SS * 4;
  float* out_probs = out + (size_t)BB * SS * 5;
  float* out_logit = out + (size_t)BB * SS * 9;

  for (int rr = 0; rr < 16; ++rr) {
    const int r = w * 16 + rr;
    const float su0 = (float)s_sum[r * 128 + l];
    const float su1 = (float)s_sum[r * 128 + 64 + l];
    float at = su0 * tw0 + su1 * tw1;
    float ad = su0 * dw0 + su1 * dw1;
#pragma unroll
    for (int o = 32; o; o >>= 1) { at += __shfl_xor(at, o); ad += __shfl_xor(ad, o); }
    const float theta = (at + tb) * 3.0f;
    const float alpha = softplusf_(ad + s_aq[r] + db);
    const float be0 = s_be[r][0], be1 = s_be[r][1], be2 = s_be[r][2];
    float h1 = bc1;
    h1 = fmaf(theta, wc1reg[0], h1);
    h1 = fmaf(alpha, wc1reg[1], h1);
    h1 = fmaf(be0, wc1reg[2], h1);
    h1 = fmaf(be1, wc1reg[3], h1);
    h1 = fmaf(be2, wc1reg[4], h1);
    h1 = fmaxf(h1, 0.f);
    s_h1[w][l] = h1;
    float hacc = hh2 ? 0.f : bc2;
    const float4* h4 = (const float4*)s_h1[w];
#pragma unroll
    for (int k = 0; k < 8; ++k) {
      const float4 hv = h4[(hh2 << 3) + k];
      hacc = fmaf(hv.x, wc2reg[4 * k + 0], hacc);
      hacc = fmaf(hv.y, wc2reg[4 * k + 1], hacc);
      hacc = fmaf(hv.z, wc2reg[4 * k + 2], hacc);
      hacc = fmaf(hv.w, wc2reg[4 * k + 3], hacc);
    }
    hacc += __shfl_xor(hacc, 1);
    const float h2 = fmaxf(hacc, 0.f);
    float p = h2 * cw * 0.5f;
#pragma unroll
    for (int o = 32; o; o >>= 1) p += __shfl_xor(p, o);
    if (l == 0) {
      const float z = p;
      const float l0 = z + cb0, l1 = z + cb1, l2 = z + cb2;
      const float s0 = sigmoidf_(l0), s1 = sigmoidf_(l1), s2 = sigmoidf_(l2);
      const float q0 = s0, q1 = s0 * s1, q2 = s0 * s1 * s2;
      const size_t bt = (size_t)rowbase + r;
      out_theta[bt] = theta;
      out_alpha[bt] = alpha;
      out_beta[bt * 3 + 0] = be0;
      out_beta[bt * 3 + 1] = be1;
      out_beta[bt * 3 + 2] = be2;
      out_logit[bt * 3 + 0] = l0;
      out_logit[bt * 3 + 1] = l1;
      out_logit[bt * 3 + 2] = l2;
      out_probs[bt * 4 + 0] = 1.f - q0;
      out_probs[bt * 4 + 1] = q0 - q1;
      out_probs[bt * 4 + 2] = q1 - q2;
      out_probs[bt * 4 + 3] = q2;
    }
  }
}

extern "C" void kernel_launch(void* const* d_in, const int* in_sizes, int n_in,
                              void* d_out, int out_size, void* d_ws, size_t ws_size,
                              hipStream_t stream) {
  const int*   q_data    = (const int*)d_in[0];
  const int*   r_data    = (const int*)d_in[1];
  const float* q_embed   = (const float*)d_in[2];
  const float* key_mem   = (const float*)d_in[3];
  const float* init_mv   = (const float*)d_in[4];
  const float* W_value   = (const float*)d_in[5];
  const float* b_value   = (const float*)d_in[6];
  const float* W_erase   = (const float*)d_in[7];
  const float* b_erase   = (const float*)d_in[8];
  const float* W_add     = (const float*)d_in[9];
  const float* b_add     = (const float*)d_in[10];
  const float* W_summary = (const float*)d_in[11];
  const float* b_summary = (const float*)d_in[12];
  const float* W_theta   = (const float*)d_in[13];
  const float* b_theta   = (const float*)d_in[14];
  const float* W_beta    = (const float*)d_in[15];
  const float* b_beta    = (const float*)d_in[16];
  const float* W_disc    = (const float*)d_in[17];
  const float* b_disc    = (const float*)d_in[18];
  const float* W_c1      = (const float*)d_in[19];
  const float* b_c1      = (const float*)d_in[20];
  const float* W_c2      = (const float*)d_in[21];
  const float* b_c2      = (const float*)d_in[22];
  const float* coral_w   = (const float*)d_in[23];
  const float* coral_b   = (const float*)d_in[24];

  float* ws = (float*)d_ws;
  size_t off = 0;
  float2* EA      = (float2*)(ws + off); off += (size_t)RROWS * VDIM * 2;
  float* w_tab    = ws + off; off += (size_t)QD * MM;
  float* Sq_tab   = ws + off; off += (size_t)QD * FDIM;
  float* aq_tab   = ws + off; off += 5120;
  float* beta_tab = ws + off; off += 15104;
  _Float16* Wh = (_Float16*)(ws + off); off += (VDIM * FDIM) / 2;
  _Float16* Rd = (_Float16*)(ws + off);

  k_pre<<<dim3(NPRE), dim3(256), 0, stream>>>(
      W_value, b_value, W_erase, b_erase, W_add, b_add,
      q_embed, key_mem, W_summary, b_summary, W_disc, W_beta, b_beta,
      EA, w_tab, Sq_tab, aq_tab, beta_tab, Wh);

  k_rec6<<<dim3(BB * 4), dim3(512), 0, stream>>>(
      q_data, r_data, init_mv, EA, w_tab, Rd);

  k_head<<<dim3((BB * SS) / 64), dim3(256), 0, stream>>>(
      q_data, Rd, Wh, Sq_tab, aq_tab, beta_tab,
      W_theta, b_theta, W_disc, b_disc,
      W_c1, b_c1, W_c2, b_c2, coral_w, coral_b, (float*)d_out);
}